// Round 28
// baseline (48.351 us; speedup 1.0000x reference)
//
#include <hip/hip_runtime.h>
#include <cstdint>

#define B_ 8
#define T_ 2048
#define C_ 1024
#define H_ 64
#define BT_ (B_ * T_)

typedef short short8 __attribute__((ext_vector_type(8)));
typedef short bh4 __attribute__((ext_vector_type(4)));
typedef float f32x4 __attribute__((ext_vector_type(4)));

__device__ inline short f2bf(float f) {
  uint32_t u = __float_as_uint(f);
  u += 0x7fffu + ((u >> 16) & 1u);  // RNE; inputs finite
  return (short)(u >> 16);
}
__device__ inline float bf2f(short s) {
  uint32_t u = ((uint32_t)(unsigned short)s) << 16;
  return __uint_as_float(u);
}

// async global->LDS, 16B per lane; LDS dest = uniform base + lane*16 (HW rule)
__device__ __forceinline__ void gl_lds16(const void* g, void* l) {
  __builtin_amdgcn_global_load_lds(
      (const __attribute__((address_space(1))) unsigned int*)g,
      (__attribute__((address_space(3))) unsigned int*)l, 16, 0, 0);
}

// batched volatile asm 16B loads; consume within the SAME iteration after a
// counted vmcnt (R20-proven). offset: 13-bit signed, <= 4095.
#define ALOADO(dst, p, off)                                        \
  asm volatile("global_load_dwordx4 %0, %1, off offset:" #off      \
               : "=v"(dst) : "v"(p) : "memory")

// ---------------------------------------------------------------------------
// prep_w: Wk/Wq/Wv [1024][64] fp32 -> Wp FRAGMENT-PACKED bf16:
// frag (c = k-chunk, nt = n-tile, f = k-half) is 1KB; lane (lg,l15) holds
// Wt[16nt+l15][64c+32f+8lg..+7] at lane*16B. Wk folded: 2^-5 * log2(e).
// ---------------------------------------------------------------------------
__global__ __launch_bounds__(256) void prep_w(
    const float* __restrict__ Wk, const float* __restrict__ Wq,
    const float* __restrict__ Wv, short* __restrict__ Wp) {
  __shared__ float wl[64][68];
  const int mat = blockIdx.x >> 4;
  const int kc = blockIdx.x & 15;
  const float* W = (mat == 0) ? Wk : (mat == 1) ? Wq : Wv;
  const float sc = (mat == 0) ? 0.03125f * 1.44269504088896f : 1.0f;
  const int t = threadIdx.x;
  const int k0 = kc * 64;
#pragma unroll
  for (int j = 0; j < 4; ++j) {
    int s = t + 256 * j;
    int kr = s >> 4, cf = s & 15;
    float4 v = *reinterpret_cast<const float4*>(&W[(size_t)(k0 + kr) * H_ + cf * 4]);
    wl[kr][cf * 4 + 0] = v.x; wl[kr][cf * 4 + 1] = v.y;
    wl[kr][cf * 4 + 2] = v.z; wl[kr][cf * 4 + 3] = v.w;
  }
  __syncthreads();
#pragma unroll
  for (int j = 0; j < 2; ++j) {
    int s = t + 256 * j;
    int n = s >> 3, g = s & 7;
    short8 o;
#pragma unroll
    for (int i = 0; i < 8; ++i) o[i] = f2bf(wl[8 * g + i][n] * sc);
    const int ng = mat * 64 + n;
    const int nt = ng >> 4, l15c = ng & 15;
    const int f = g >> 2, lg2 = g & 3;
    short* dst = Wp + (((size_t)(kc * 12 + nt) * 2 + f) << 9) +
                 ((lg2 << 4) + l15c) * 8;
    *reinterpret_cast<short8*>(dst) = o;
  }
}

// ---------------------------------------------------------------------------
// proj: R20 EXACT (best measured). M=32 x N=192, 512 blocks x 256 thr.
// W asm-batch-loaded from fragment-packed Wp (vmcnt(2): x stays in flight);
// x staged via gl_lds double-buffer + __syncthreads.
// ---------------------------------------------------------------------------
__global__ __launch_bounds__(256, 1) void proj_kernel(
    const float* __restrict__ x, const short* __restrict__ Wp,
    short* __restrict__ Kp, short* __restrict__ Qp, short* __restrict__ Vt) {
  __shared__ float xs[2][32 * 64];  // 8KB each
  const int t = threadIdx.x;
  const int w = t >> 6, lane = t & 63;
  const int l15 = lane & 15, lg = lane >> 4;
  const int rg = w >> 1, ch = w & 1;
  const int rowBase = blockIdx.x * 32;

  f32x4 acc[6];
  const f32x4 zf = {0.f, 0.f, 0.f, 0.f};
#pragma unroll
  for (int i = 0; i < 6; ++i) acc[i] = zf;

  auto stageX = [&](int buf, int k0) {
#pragma unroll
    for (int j = 0; j < 2; ++j) {
      const int seg = w * 2 + j;  // 8 segs of 4 rows
      const int r = seg * 4 + (lane >> 4);
      const float* g =
          &x[(size_t)(rowBase + r) * C_ + k0 + (((lane & 15) ^ (r & 7)) << 2)];
      gl_lds16(g, (char*)&xs[buf][0] + seg * 1024);
    }
  };

  stageX(0, 0);

#pragma unroll 1
  for (int it = 0; it < 16; ++it) {
    __syncthreads();  // drains x stage for this buffer
    const int cb = it & 1;
    short8 bw[12];
    const short* wb0 = Wp + (((size_t)(it * 12 + 6 * ch)) << 10) + lane * 8;
    const short* wb1 = wb0 + 2048;
    const short* wb2 = wb0 + 4096;
    ALOADO(bw[0], wb0, 0);    ALOADO(bw[1], wb0, 1024);
    ALOADO(bw[2], wb0, 2048); ALOADO(bw[3], wb0, 3072);
    ALOADO(bw[4], wb1, 0);    ALOADO(bw[5], wb1, 1024);
    ALOADO(bw[6], wb1, 2048); ALOADO(bw[7], wb1, 3072);
    ALOADO(bw[8], wb2, 0);    ALOADO(bw[9], wb2, 1024);
    ALOADO(bw[10], wb2, 2048); ALOADO(bw[11], wb2, 3072);
    __builtin_amdgcn_sched_barrier(0);
    if (it < 15) stageX(cb ^ 1, (it + 1) * 64);  // x gl_lds AFTER W loads
    __builtin_amdgcn_sched_barrier(0);
    if (it < 15) {
      asm volatile("s_waitcnt vmcnt(2)" ::: "memory");  // W done; x in flight
    } else {
      asm volatile("s_waitcnt vmcnt(0)" ::: "memory");
    }
    __builtin_amdgcn_sched_barrier(0);  // rule #18

    const int arow = 16 * rg + l15;
    const int x7 = arow & 7;
    const float* xrow = &xs[cb][arow * 64];
    float4 fa = *reinterpret_cast<const float4*>(xrow + (((2 * lg) ^ x7) << 2));
    float4 fb = *reinterpret_cast<const float4*>(xrow + (((2 * lg + 1) ^ x7) << 2));
    float4 fc = *reinterpret_cast<const float4*>(xrow + (((2 * lg + 8) ^ x7) << 2));
    float4 fd = *reinterpret_cast<const float4*>(xrow + (((2 * lg + 9) ^ x7) << 2));
    short8 a0, a1;
    a0[0] = f2bf(fa.x); a0[1] = f2bf(fa.y); a0[2] = f2bf(fa.z); a0[3] = f2bf(fa.w);
    a0[4] = f2bf(fb.x); a0[5] = f2bf(fb.y); a0[6] = f2bf(fb.z); a0[7] = f2bf(fb.w);
    a1[0] = f2bf(fc.x); a1[1] = f2bf(fc.y); a1[2] = f2bf(fc.z); a1[3] = f2bf(fc.w);
    a1[4] = f2bf(fd.x); a1[5] = f2bf(fd.y); a1[6] = f2bf(fd.z); a1[7] = f2bf(fd.w);
#pragma unroll
    for (int nt = 0; nt < 6; ++nt) {
      acc[nt] = __builtin_amdgcn_mfma_f32_16x16x32_bf16(a0, bw[2 * nt], acc[nt], 0, 0, 0);
      acc[nt] = __builtin_amdgcn_mfma_f32_16x16x32_bf16(a1, bw[2 * nt + 1], acc[nt], 0, 0, 0);
    }
  }

  // ---- epilogue ----
  const int strip = blockIdx.x * 2 + rg;
  const int rb = strip * 16;
#pragma unroll
  for (int nt = 0; nt < 6; ++nt) {
    const int ntg = 6 * ch + nt;
    if (ntg < 8) {
      short* O = (ntg < 4) ? Kp : Qp;
      const int col = (ntg & 3) * 16 + l15;
#pragma unroll
      for (int r = 0; r < 4; ++r)
        O[(size_t)(rb + lg * 4 + r) * H_ + col] = f2bf(acc[nt][r]);
    }
  }
  __syncthreads();  // xs dead; reuse for V transpose
  if (ch == 1) {
    short* vl = reinterpret_cast<short*>(&xs[0][0]) + rg * (16 * 66);
#pragma unroll
    for (int nt = 2; nt < 6; ++nt)
#pragma unroll
      for (int r = 0; r < 4; ++r)
        vl[(lg * 4 + r) * 66 + (nt - 2) * 16 + l15] = f2bf(acc[nt][r]);
    asm volatile("s_waitcnt lgkmcnt(0)" ::: "memory");
    short8 o0, o1;
#pragma unroll
    for (int i = 0; i < 8; ++i) o0[i] = vl[i * 66 + lane];
#pragma unroll
    for (int i = 0; i < 8; ++i) o1[i] = vl[(8 + i) * 66 + lane];
    const int bb = strip >> 7, tb = (strip & 127) * 16;
    short* dst = &Vt[((size_t)bb * H_ + lane) * T_ + tb];
    *reinterpret_cast<short8*>(dst) = o0;
    *reinterpret_cast<short8*>(dst + 8) = o1;
  }
}

// ---------------------------------------------------------------------------
// attn: R26 exact. 512 blocks x 512 thr (8 row-groups of 16 rows).
// Block = (batch, 128-row strip, k-quarter). Partials in bf16 -> Pg; m,l f32.
// ---------------------------------------------------------------------------
__global__ __launch_bounds__(512) void attn_kernel(
    const short* __restrict__ Kq, const short* __restrict__ Qk,
    const short* __restrict__ Vt, short* __restrict__ Pg,
    float* __restrict__ Mg) {
  __shared__ short Ks[4][64 * 64];
  __shared__ short Vs[4][64 * 64];
  const int t = threadIdx.x, w = t >> 6, lane = t & 63;
  const int l15 = lane & 15, lg = lane >> 4;
  const int batch = blockIdx.x & 7;
  const int rest = blockIdx.x >> 3;
  const int qh = rest & 3;
  const int g = rest >> 2;
  const int sidx = (g < 8) ? (15 - g) : (g - 8);
  const int rg = w;
  const short* Kb = Kq + (size_t)batch * T_ * H_;
  const short* Qb = Qk + (size_t)batch * T_ * H_;
  const short* Vb = Vt + (size_t)batch * H_ * T_;
  const f32x4 zf = {0.f, 0.f, 0.f, 0.f};
  const int k7 = l15 & 7;

  const int qbase = sidx * 128;
  const int qrow = qbase + rg * 16 + l15;
  const short8 qa0 = *reinterpret_cast<const short8*>(&Kb[(size_t)qrow * H_ + lg * 8]);
  const short8 qa1 = *reinterpret_cast<const short8*>(&Kb[(size_t)qrow * H_ + lg * 8 + 32]);
  const int ntop = 2 * sidx + 1;
  const int nlist = (ntop >= qh) ? (((ntop - qh) >> 2) + 1) : 0;
  const int np = (nlist + 1) >> 1;

  const int tp = w >> 2, kind = (w >> 1) & 1, q2 = w & 1;
  const int srow = lane >> 3;
  const int ssw = ((lane & 7) ^ srow) << 3;
  auto stage = [&](int per) {
    const int le = 2 * per + tp;
    if (le >= nlist) return;
    const int gkt = 4 * le + qh;
    const int buf = (per & 1) * 2 + tp;
    const int kbase = gkt * 64;
    if (kind == 0) {
#pragma unroll
      for (int g2 = 0; g2 < 4; ++g2) {
        const int gg = q2 * 4 + g2;
        gl_lds16(&Qb[(size_t)(kbase + gg * 8 + srow) * H_ + ssw],
                 (char*)&Ks[buf][0] + gg * 1024);
      }
    } else {
#pragma unroll
      for (int g2 = 0; g2 < 4; ++g2) {
        const int gg = q2 * 4 + g2;
        gl_lds16(&Vb[(size_t)(gg * 8 + srow) * T_ + kbase + ssw],
                 (char*)&Vs[buf][0] + gg * 1024);
      }
    }
  };

  f32x4 O[4];
#pragma unroll
  for (int i = 0; i < 4; ++i) O[i] = zf;
  float m = -1e30f, l = 0.f;

  stage(0);

#pragma unroll 1
  for (int i = 0; i < np; ++i) {
    __syncthreads();
    if (i + 1 < np) stage(i + 1);
#pragma unroll 1
    for (int tt = 0; tt < 2; ++tt) {
      const int le = 2 * i + tt;
      if (le < nlist) {
        const int gkt = 4 * le + qh;
        const int cb = (i & 1) * 2 + tt;
        const int kbase = gkt * 64;
        f32x4 S[4];
        __builtin_amdgcn_s_setprio(1);
#pragma unroll
        for (int nt = 0; nt < 4; ++nt) {
          S[nt] = zf;
          const short* krow = &Ks[cb][(16 * nt + l15) * 64];
          short8 kf0 = *reinterpret_cast<const short8*>(&krow[(lg ^ k7) << 3]);
          short8 kf1 = *reinterpret_cast<const short8*>(&krow[((4 + lg) ^ k7) << 3]);
          S[nt] = __builtin_amdgcn_mfma_f32_16x16x32_bf16(kf0, qa0, S[nt], 0, 0, 0);
          S[nt] = __builtin_amdgcn_mfma_f32_16x16x32_bf16(kf1, qa1, S[nt], 0, 0, 0);
        }
        __builtin_amdgcn_s_setprio(0);
        if (gkt >= 2 * sidx) {
#pragma unroll
          for (int nt = 0; nt < 4; ++nt) {
            const int klo = kbase + 16 * nt + 4 * lg;
#pragma unroll
            for (int r = 0; r < 4; ++r)
              if (klo + r > qrow) S[nt][r] = -1e30f;
          }
        }
        float mx0 = fmaxf(fmaxf(S[0][0], S[0][1]), fmaxf(S[0][2], S[0][3]));
        float mx1 = fmaxf(fmaxf(S[1][0], S[1][1]), fmaxf(S[1][2], S[1][3]));
        float mx2 = fmaxf(fmaxf(S[2][0], S[2][1]), fmaxf(S[2][2], S[2][3]));
        float mx3 = fmaxf(fmaxf(S[3][0], S[3][1]), fmaxf(S[3][2], S[3][3]));
        float mx = fmaxf(fmaxf(mx0, mx1), fmaxf(mx2, mx3));
        mx = fmaxf(mx, __shfl_xor(mx, 16));
        mx = fmaxf(mx, __shfl_xor(mx, 32));
        const float mn = fmaxf(m, mx);
        const float scv = exp2f(m - mn);
        m = mn;
        float rs = 0.f;
#pragma unroll
        for (int nt = 0; nt < 4; ++nt)
#pragma unroll
          for (int r = 0; r < 4; ++r) {
            const float pv = exp2f(S[nt][r] - mn);
            S[nt][r] = pv;
            rs += pv;
          }
        rs += __shfl_xor(rs, 16);
        rs += __shfl_xor(rs, 32);
        l = l * scv + rs;
#pragma unroll
        for (int nt = 0; nt < 4; ++nt) O[nt] *= scv;
        const int d7 = l15 & 7;
        const int vo = 4 * (lg & 1);
        __builtin_amdgcn_s_setprio(1);
#pragma unroll
        for (int kc = 0; kc < 2; ++kc) {
          short8 pa;
#pragma unroll
          for (int jj = 0; jj < 8; ++jj)
            pa[jj] = f2bf(S[2 * kc + (jj >> 2)][jj & 3]);
          const int slo = ((4 * kc + (lg >> 1)) ^ d7) << 3;
          const int shi = ((4 * kc + 2 + (lg >> 1)) ^ d7) << 3;
#pragma unroll
          for (int nt = 0; nt < 4; ++nt) {
            const short* vrow = &Vs[cb][(16 * nt + l15) * 64];
            const bh4 vlo = *reinterpret_cast<const bh4*>(&vrow[slo + vo]);
            const bh4 vhi = *reinterpret_cast<const bh4*>(&vrow[shi + vo]);
            short8 vf;
            vf[0] = vlo[0]; vf[1] = vlo[1]; vf[2] = vlo[2]; vf[3] = vlo[3];
            vf[4] = vhi[0]; vf[5] = vhi[1]; vf[6] = vhi[2]; vf[7] = vhi[3];
            O[nt] = __builtin_amdgcn_mfma_f32_16x16x32_bf16(vf, pa, O[nt], 0, 0, 0);
          }
        }
        __builtin_amdgcn_s_setprio(0);
      }
    }
  }

  // publish partials: Pg in bf16 (halved traffic); Mg (m,l) in f32
  const size_t gr = (size_t)batch * T_ + qrow;
#pragma unroll
  for (int nt = 0; nt < 4; ++nt) {
    bh4 pk;
    pk[0] = f2bf(O[nt][0]); pk[1] = f2bf(O[nt][1]);
    pk[2] = f2bf(O[nt][2]); pk[3] = f2bf(O[nt][3]);
    *reinterpret_cast<bh4*>(&Pg[((size_t)qh * BT_ + gr) * H_ + 16 * nt + 4 * lg]) = pk;
  }
  if (lg == 0) {
    Mg[((size_t)qh * BT_ + gr) * 2 + 0] = m;
    Mg[((size_t)qh * BT_ + gr) * 2 + 1] = l;
  }
}

// ---------------------------------------------------------------------------
// combine: 4-way merge of bf16 k-quarter partials per row (R26 exact).
// ---------------------------------------------------------------------------
__global__ __launch_bounds__(256) void combine_kernel(
    const short* __restrict__ Pg, const float* __restrict__ Mg,
    float* __restrict__ out) {
  const int t = threadIdx.x;
#pragma unroll
  for (int k = 0; k < 2; ++k) {
    const int task = blockIdx.x * 512 + k * 256 + t;
    const int row = task >> 4;
    const int c4 = task & 15;
    float Mh[4], Lh[4];
#pragma unroll
    for (int h = 0; h < 4; ++h) {
      Mh[h] = Mg[((size_t)h * BT_ + row) * 2 + 0];
      Lh[h] = Mg[((size_t)h * BT_ + row) * 2 + 1];
    }
    const float M = fmaxf(fmaxf(Mh[0], Mh[1]), fmaxf(Mh[2], Mh[3]));
    float L = 0.f;
    f32x4 o = {0.f, 0.f, 0.f, 0.f};
#pragma unroll
    for (int h = 0; h < 4; ++h) {
      const float e = exp2f(Mh[h] - M);
      L += Lh[h] * e;
      const bh4 pb =
          *reinterpret_cast<const bh4*>(&Pg[((size_t)h * BT_ + row) * H_ + c4 * 4]);
      o[0] += bf2f(pb[0]) * e;
      o[1] += bf2f(pb[1]) * e;
      o[2] += bf2f(pb[2]) * e;
      o[3] += bf2f(pb[3]) * e;
    }
    const f32x4 res = o * (1.f / L);
    *reinterpret_cast<f32x4*>(&out[(size_t)row * H_ + c4 * 4]) = res;
  }
}

extern "C" void kernel_launch(void* const* d_in, const int* in_sizes, int n_in,
                              void* d_out, int out_size, void* d_ws, size_t ws_size,
                              hipStream_t stream) {
  const float* x = (const float*)d_in[0];
  const float* Wk = (const float*)d_in[1];
  const float* Wq = (const float*)d_in[2];
  const float* Wv = (const float*)d_in[3];
  float* out = (float*)d_out;

  short* Kp = (short*)d_ws;                  // [BT][64] bf16 (queries: x@Wk, scale*log2e folded)
  short* Qp = Kp + (size_t)BT_ * H_;         // [BT][64] bf16 (keys:    x@Wq)
  short* Vt = Qp + (size_t)BT_ * H_;         // [8][64][2048] bf16 (values^T)
  short* Wp = Vt + (size_t)BT_ * H_;         // [384KB] fragment-packed W bf16
  short* Pg = Wp + 192 * C_;                 // [4][BT][64] bf16 partials (8MB)
  float* Mg = (float*)(Pg + (size_t)4 * BT_ * H_);  // [4][BT][2] f32 (m,l)

  hipLaunchKernelGGL(prep_w, dim3(48), dim3(256), 0, stream, Wk, Wq, Wv, Wp);
  hipLaunchKernelGGL(proj_kernel, dim3(512), dim3(256), 0, stream, x, Wp, Kp, Qp, Vt);
  hipLaunchKernelGGL(attn_kernel, dim3(512), dim3(512), 0, stream, Kp, Qp, Vt, Pg, Mg);
  hipLaunchKernelGGL(combine_kernel, dim3(512), dim3(256), 0, stream, Pg, Mg, out);
}